// Round 7
// baseline (609.296 us; speedup 1.0000x reference)
//
#include <hip/hip_runtime.h>
#include <hip/hip_bf16.h>

#define TPB 256
#define NCODES 1024
#define DIMS 256
#define PIXB 64
#define XPAD 264      // bf16 transpose-tile row stride (ushorts)
#define EPAD 40       // es row stride (ushorts) = 80 B (R3-proven bank spread)
#define XS3 68        // phase-3 fp32 x-stage row stride (floats)
#define DELTA 3.0f    // screening margin; bf16 dot error worst-case ~2.6 in distance units
#define CAP 8         // candidates per pixel; overflow -> exact full rescan

typedef __attribute__((ext_vector_type(8))) short bf16x8;
typedef __attribute__((ext_vector_type(4))) float f32x4;

__device__ __forceinline__ unsigned fkey(float f) {
    unsigned u = __float_as_uint(f);
    return (u & 0x80000000u) ? ~u : (u | 0x80000000u);
}
__device__ __forceinline__ float funkey(unsigned k) {
    return (k & 0x80000000u) ? __uint_as_float(k & 0x7fffffffu) : __uint_as_float(~k);
}

// ---- zb kernel: z (t, d, n) fp32 -> zb (t, n, d) bf16, via LDS tile transpose ----
__global__ __launch_bounds__(TPB) void zb_kernel(const float* __restrict__ z,
                                                 ushort* __restrict__ zb) {
    __shared__ __align__(16) ushort xs[PIXB * XPAD];
    const int tid = threadIdx.x;
    const int w   = tid >> 6;
    const int L   = tid & 63;
    const int pixbase = blockIdx.x * PIXB;
    const int t  = pixbase >> 12;
    const int n0 = pixbase & 4095;
    {   // coalesced float4 z loads, bf16 convert, transposed LDS store (R4-verified)
        const int pq = L & 15;
        const int dq = L >> 4;
#pragma unroll
        for (int i = 0; i < 16; ++i) {
            const int d = w * 64 + i * 4 + dq;
            const float4 v = *(const float4*)(z + (((size_t)(t * DIMS + d)) << 12) + n0 + 4 * pq);
            __hip_bfloat16 h0 = __float2bfloat16(v.x), h1 = __float2bfloat16(v.y);
            __hip_bfloat16 h2 = __float2bfloat16(v.z), h3 = __float2bfloat16(v.w);
            xs[(4 * pq + 0) * XPAD + d] = *(ushort*)&h0;
            xs[(4 * pq + 1) * XPAD + d] = *(ushort*)&h1;
            xs[(4 * pq + 2) * XPAD + d] = *(ushort*)&h2;
            xs[(4 * pq + 3) * XPAD + d] = *(ushort*)&h3;
        }
    }
    __syncthreads();
    uint4* zo = (uint4*)zb;
#pragma unroll
    for (int i = 0; i < 8; ++i) {        // 2048 uint4 = 64 rows x 32 units, coalesced out
        const int u   = i * 256 + tid;
        const int row = u >> 5;
        const int un  = u & 31;
        zo[(((size_t)(t * 4096 + n0 + row)) << 5) + un] = *(const uint4*)&xs[row * XPAD + un * 8];
    }
}

// ---- prep: ebc = bf16(emb) chunk-major [cc][kc][256 codes][32 dims]; e2 exact fp32 ----
__global__ __launch_bounds__(64) void prep_kernel(const float* __restrict__ emb,
                                                  ushort* __restrict__ ebc,
                                                  float* __restrict__ e2) {
    const int c = blockIdx.x;
    const int l = threadIdx.x;           // lane l holds dims 4l..4l+3
    float4 v = *(const float4*)(emb + (size_t)c * DIMS + 4 * l);
    __hip_bfloat16 h0 = __float2bfloat16(v.x), h1 = __float2bfloat16(v.y);
    __hip_bfloat16 h2 = __float2bfloat16(v.z), h3 = __float2bfloat16(v.w);
    ushort4 u4;
    u4.x = *(ushort*)&h0; u4.y = *(ushort*)&h1; u4.z = *(ushort*)&h2; u4.w = *(ushort*)&h3;
    const int kc   = l >> 3;
    const int u    = (l & 7) >> 1;       // 16B part within row (holds dims u*8..u*8+7)
    const int half = l & 1;
    *(ushort4*)(ebc + (size_t)((c >> 8) * 8 + kc) * 8192 + ((c & 255) * 4 + u) * 8 + half * 4) = u4;
    float s = v.x * v.x + v.y * v.y + v.z * v.z + v.w * v.w;
#pragma unroll
    for (int off = 1; off < 64; off <<= 1) s += __shfl_xor(s, off);
    if (l == 0) e2[c] = s;
}

template <bool ZB_GLOBAL>
__global__ __launch_bounds__(TPB, 2) void vq_kernel(const float* __restrict__ z,
                                                    const float* __restrict__ emb,
                                                    const ushort* __restrict__ ebc,
                                                    const ushort* __restrict__ zb,
                                                    const float* __restrict__ e2g,
                                                    int* __restrict__ out) {
    // ZB_GLOBAL: 20480 + 4096 + 256 + 256 + 2048 = 27136 B -> ~6 blocks/CU
    // fallback:  +33792 (xs) = 60928 B -> 2 blocks/CU (R3 regime)
    __shared__ __align__(16) ushort es[256 * EPAD];    // e tile; phase-3 aliases as fp32 x-stage
    __shared__ float    e2s[NCODES];
    __shared__ unsigned minkey[PIXB];
    __shared__ int      cnt[PIXB];
    __shared__ int      cand[PIXB * CAP];
    extern __shared__ ushort xsdyn[];                  // fallback-only bf16 x tile (64*XPAD)

    const int tid = threadIdx.x;
    const int w   = tid >> 6;
    const int L   = tid & 63;
    const int col = L & 15;       // MFMA col (pixel in B / code in A)
    const int q   = L >> 4;       // MFMA quad (k-slice q*8..q*8+7)
    const int pixbase = blockIdx.x * PIXB;
    const int t  = pixbase >> 12;
    const int n0 = pixbase & 4095;

    if (!ZB_GLOBAL) {   // fallback phase-1: in-LDS bf16 transpose of this block's z
        const int pq = L & 15;
        const int dq = L >> 4;
#pragma unroll
        for (int i = 0; i < 16; ++i) {
            const int d = w * 64 + i * 4 + dq;
            const float4 v = *(const float4*)(z + (((size_t)(t * DIMS + d)) << 12) + n0 + 4 * pq);
            __hip_bfloat16 h0 = __float2bfloat16(v.x), h1 = __float2bfloat16(v.y);
            __hip_bfloat16 h2 = __float2bfloat16(v.z), h3 = __float2bfloat16(v.w);
            xsdyn[(4 * pq + 0) * XPAD + d] = *(ushort*)&h0;
            xsdyn[(4 * pq + 1) * XPAD + d] = *(ushort*)&h1;
            xsdyn[(4 * pq + 2) * XPAD + d] = *(ushort*)&h2;
            xsdyn[(4 * pq + 3) * XPAD + d] = *(ushort*)&h3;
        }
    }
#pragma unroll
    for (int i = 0; i < 4; ++i) e2s[tid + 256 * i] = e2g[tid + 256 * i];
    if (tid < 64) { minkey[tid] = 0xFFFFFFFFu; cnt[tid] = 0; }
    __syncthreads();

    const uint4* __restrict__ esrc = (const uint4*)ebc;

    // ---- phase 2: MFMA screening ----
#pragma unroll 1
    for (int cc = 0; cc < 4; ++cc) {
        f32x4 acc[4][4];
#pragma unroll
        for (int mt = 0; mt < 4; ++mt)
#pragma unroll
            for (int nt = 0; nt < 4; ++nt) acc[mt][nt] = (f32x4){0.f, 0.f, 0.f, 0.f};

#pragma unroll 1
        for (int kc = 0; kc < 8; ++kc) {
            if (kc) __syncthreads();      // prev af reads done (cc>0,kc=0 covered by epilogue barrier)
            {   // stage es: coalesced 1KB/wave reads from chunk-major ebc, reg->LDS
                const size_t b = (size_t)(cc * 8 + kc) * 1024 + tid;
                uint4 rd[4];
#pragma unroll
                for (int j = 0; j < 4; ++j) rd[j] = esrc[b + j * 256];
#pragma unroll
                for (int j = 0; j < 4; ++j)
                    *(uint4*)&es[((tid >> 2) + j * 64) * EPAD + (tid & 3) * 8] = rd[j];
            }
            __syncthreads();

            bf16x8 af[4], bfr[4];
#pragma unroll
            for (int mt = 0; mt < 4; ++mt)
                af[mt] = *(const bf16x8*)&es[(w * 64 + mt * 16 + col) * EPAD + q * 8];
#pragma unroll
            for (int nt = 0; nt < 4; ++nt) {
                if (ZB_GLOBAL)
                    bfr[nt] = *(const bf16x8*)(zb + ((size_t)(t * 4096 + n0 + nt * 16 + col) << 8)
                                                  + kc * 32 + q * 8);
                else
                    bfr[nt] = *(const bf16x8*)&xsdyn[(nt * 16 + col) * XPAD + kc * 32 + q * 8];
            }
#pragma unroll
            for (int mt = 0; mt < 4; ++mt)
#pragma unroll
                for (int nt = 0; nt < 4; ++nt)
                    acc[mt][nt] = __builtin_amdgcn_mfma_f32_16x16x32_bf16(
                        af[mt], bfr[nt], acc[mt][nt], 0, 0, 0);
        }

        // epilogue: s = e2[c] - 2*dot ; C layout col=px, row=q*4+r_
        f32x4 e2r[4];
#pragma unroll
        for (int mt = 0; mt < 4; ++mt)
            e2r[mt] = *(const f32x4*)&e2s[cc * 256 + w * 64 + mt * 16 + q * 4];
#pragma unroll
        for (int nt = 0; nt < 4; ++nt) {
            float m = 3.4e38f;
#pragma unroll
            for (int mt = 0; mt < 4; ++mt)
#pragma unroll
                for (int r_ = 0; r_ < 4; ++r_)
                    m = fminf(m, e2r[mt][r_] - 2.f * acc[mt][nt][r_]);
            m = fminf(m, __shfl_xor(m, 16));
            m = fminf(m, __shfl_xor(m, 32));
            if (q == 0) atomicMin(&minkey[nt * 16 + col], fkey(m));
        }
        __syncthreads();                  // minkey visible; also fences es for next cc
#pragma unroll
        for (int nt = 0; nt < 4; ++nt) {
            const int px = nt * 16 + col;
            const float thr = funkey(minkey[px]) + DELTA;   // running min -> superset guarantee
#pragma unroll
            for (int mt = 0; mt < 4; ++mt)
#pragma unroll
                for (int r_ = 0; r_ < 4; ++r_) {
                    float s = e2r[mt][r_] - 2.f * acc[mt][nt][r_];
                    if (s <= thr) {
                        int pos = atomicAdd(&cnt[px], 1);
                        if (pos < CAP)
                            cand[px * CAP + pos] = cc * 256 + w * 64 + mt * 16 + q * 4 + r_;
                    }
                }
        }
    }
    __syncthreads();                      // candidate lists final; es dead -> reuse as x-stage

    // ---- phase 3: exact fp32 rescore from LDS-staged z chunks (R6-verified) ----
    float* xstage = (float*)es;           // 64 x XS3 fp32 = 17408 B <= 20480 B
    const int px  = w * 16 + (L & 15);
    const int n   = cnt[px];
    const bool ovf = (n > CAP);
    const int ns  = ovf ? 0 : n;
    const int s0  = L >> 4;
    const int c0  = (s0 < ns)     ? cand[px * CAP + s0]     : -1;
    const int c1  = (s0 + 4 < ns) ? cand[px * CAP + s0 + 4] : -1;
    float a0 = 0.f, a1 = 0.f;

#pragma unroll 1
    for (int dc = 0; dc < 4; ++dc) {
        if (dc) __syncthreads();
        {   // stage 64 dims x 64 px fp32; lane L = px (coalesced 256B per instr)
            const float* zp = z + (((size_t)(t * DIMS + dc * 64 + w * 16)) << 12) + n0 + L;
            float* xrow = xstage + L * XS3 + w * 16;
#pragma unroll
            for (int j = 0; j < 16; ++j)
                xrow[j] = zp[(size_t)j << 12];
        }
        __syncthreads();
        const float* xv = xstage + px * XS3;
        if (c0 >= 0) {
            const float4* ep = (const float4*)(emb + (size_t)c0 * DIMS + dc * 64);
#pragma unroll
            for (int d4 = 0; d4 < 16; ++d4) {
                float4 x4 = *(const float4*)(xv + 4 * d4);
                float4 e4 = ep[d4];
                a0 += x4.x * e4.x + x4.y * e4.y + x4.z * e4.z + x4.w * e4.w;
            }
        }
        if (c1 >= 0) {
            const float4* ep = (const float4*)(emb + (size_t)c1 * DIMS + dc * 64);
#pragma unroll
            for (int d4 = 0; d4 < 16; ++d4) {
                float4 x4 = *(const float4*)(xv + 4 * d4);
                float4 e4 = ep[d4];
                a1 += x4.x * e4.x + x4.y * e4.y + x4.z * e4.z + x4.w * e4.w;
            }
        }
    }
    {   // per-lane best of 2 slots, then combine 4 lanes sharing this px
        float bd = 3.4e38f; int bi_ = 0x7fffffff;
        if (c0 >= 0) { float s = e2g[c0] - 2.f * a0; if (s < bd || (s == bd && c0 < bi_)) { bd = s; bi_ = c0; } }
        if (c1 >= 0) { float s = e2g[c1] - 2.f * a1; if (s < bd || (s == bd && c1 < bi_)) { bd = s; bi_ = c1; } }
#pragma unroll
        for (int off = 16; off < 64; off <<= 1) {
            float d2 = __shfl_xor(bd, off);
            int   i2 = __shfl_xor(bi_, off);
            if (d2 < bd || (d2 == bd && i2 < bi_)) { bd = d2; bi_ = i2; }
        }
        if (L < 16 && !ovf) out[pixbase + px] = bi_;
    }

    // overflow fallback (rare): exact full scan
#pragma unroll 1
    for (int pi = 0; pi < 16; ++pi) {
        const int fpx = w * 16 + pi;
        if (cnt[fpx] <= CAP) continue;    // wave-uniform
        const float* zp = z + (((size_t)t * DIMS + 4 * L) << 12) + n0 + fpx;
        float x0 = zp[0];
        float x1 = zp[(size_t)1 << 12];
        float x2 = zp[(size_t)2 << 12];
        float x3 = zp[(size_t)3 << 12];
        float bs = 3.4e38f;
        int   bi = 0;
        for (int c = 0; c < NCODES; ++c) {
            float4 ev = *(const float4*)(emb + (size_t)c * DIMS + 4 * L);
            float p = x0 * ev.x + x1 * ev.y + x2 * ev.z + x3 * ev.w;
#pragma unroll
            for (int off = 1; off < 64; off <<= 1) p += __shfl_xor(p, off);
            float s = e2g[c] - 2.f * p;
            if (s < bs || (s == bs && c < bi)) { bs = s; bi = c; }
        }
        if (L == 0) out[pixbase + fpx] = bi;
    }
}

extern "C" void kernel_launch(void* const* d_in, const int* in_sizes, int n_in,
                              void* d_out, int out_size, void* d_ws, size_t ws_size,
                              hipStream_t stream) {
    const float* z   = (const float*)d_in[0];   // (16,256,64,64) fp32
    const float* emb = (const float*)d_in[1];   // (1024,256) fp32
    int* out = (int*)d_out;                     // (16,64,64) int32

    const size_t zb_bytes  = (size_t)16 * 4096 * DIMS * sizeof(ushort);   // 32 MB
    const size_t ebc_bytes = (size_t)NCODES * DIMS * sizeof(ushort);      // 512 KB

    if (ws_size >= zb_bytes + ebc_bytes + 4096) {
        ushort* zbp = (ushort*)d_ws;
        ushort* ebc = (ushort*)((char*)d_ws + zb_bytes);
        float*  e2  = (float*)((char*)d_ws + zb_bytes + ebc_bytes);
        prep_kernel<<<NCODES, 64, 0, stream>>>(emb, ebc, e2);
        zb_kernel<<<(16 * 64 * 64) / PIXB, TPB, 0, stream>>>(z, zbp);
        vq_kernel<true><<<(16 * 64 * 64) / PIXB, TPB, 0, stream>>>(z, emb, ebc, zbp, e2, out);
    } else {
        ushort* ebc = (ushort*)d_ws;
        float*  e2  = (float*)((char*)d_ws + ebc_bytes);
        prep_kernel<<<NCODES, 64, 0, stream>>>(emb, ebc, e2);
        vq_kernel<false><<<(16 * 64 * 64) / PIXB, TPB, PIXB * XPAD * sizeof(ushort), stream>>>(
            z, emb, ebc, nullptr, e2, out);
    }
}